// Round 1
// baseline (402.049 us; speedup 1.0000x reference)
//
#include <hip/hip_runtime.h>
#include <hip/hip_bf16.h>

typedef unsigned int uint;
typedef unsigned short ushort;

constexpr int Bn = 256, Sn = 512, Vn = 32000, Dn = 100, Hn = 75, Ln = 128;
constexpr int EW = 80;    // embW row stride (floats), cols 75..79 zero
constexpr int KP = 96;    // h_all row stride (f16) = MFMA K-pad (3 x 32)
constexpr int W2S = 80;   // w2p row stride (f16)

// workspace layout (float units)
constexpr size_t OFF_EMBW = 0;                          // 32000*80   = 2,560,000 f
constexpr size_t OFF_HALL = OFF_EMBW + (size_t)Vn*EW;   // 131072*96 f16 = 6,291,456 f
constexpr size_t OFF_W2P  = OFF_HALL + (size_t)Bn*Sn*KP/2; // 80*80 f16 = 3200 f
constexpr size_t OFF_WOH  = OFF_W2P + 3200;             // 80*96 f16  = 3840 f
constexpr size_t OFF_WFH  = OFF_WOH + 3840;             // 128*96 f16 = 6144 f

typedef __attribute__((ext_vector_type(2))) _Float16 half2_t;
typedef __attribute__((ext_vector_type(8))) _Float16 half8;
typedef __attribute__((ext_vector_type(4))) float floatx4;

__device__ __forceinline__ ushort f2h(float f){
    union { _Float16 h; ushort u; } v; v.h = (_Float16)f; return v.u;
}
__device__ __forceinline__ half2_t as_h2(uint u){
    union { uint u; half2_t h; } v; v.u = u; return v.h;
}
__device__ __forceinline__ float sigmoidf(float z){ return 1.f/(1.f + __expf(-z)); }

// ---------------------------------------------------------------------------
// Prep: W2 -> [80][80] f16 (pad 0), Wo -> [80][96] f16, Wfc -> [128][96] f16,
// zero h_all pad cols 80..95 (so k_out never reads garbage).
// ---------------------------------------------------------------------------
__global__ __launch_bounds__(256) void k_wprep(
    const float* __restrict__ W2, const float* __restrict__ Wo,
    const float* __restrict__ Wfc, ushort* __restrict__ w2p,
    ushort* __restrict__ woh, ushort* __restrict__ wfh, ushort* __restrict__ h_all)
{
    const int tid = blockIdx.x*256 + threadIdx.x;
    const int stride = gridDim.x*256;
    for (int i = tid; i < 80*W2S; i += stride){
        int r = i / W2S, k = i % W2S;
        w2p[i] = (r < Hn && k < Hn) ? f2h(W2[r*Hn + k]) : (ushort)0;
    }
    for (int i = tid; i < 80*KP; i += stride){
        int r = i / KP, k = i % KP;
        woh[i] = (r < Hn && k < Hn) ? f2h(Wo[r*Hn + k]) : (ushort)0;
    }
    for (int i = tid; i < Ln*KP; i += stride){
        int l = i / KP, k = i % KP;
        wfh[i] = (k < Hn) ? f2h(Wfc[l*Hn + k]) : (ushort)0;
    }
    // h_all[row][80..95] = 0  (8 uints per row)
    uint* hu = (uint*)h_all;
    for (int i = tid; i < Bn*Sn*8; i += stride){
        int row = i >> 3, c = i & 7;
        hu[(size_t)row*48 + 40 + c] = 0u;
    }
}

// ---------------------------------------------------------------------------
// embW[v][j] = sum_d emb[v][d]*W1[j][d] + b1[j] + b2[j], stride EW=80,
// cols 75..79 zero. One wave per 64 vocab rows; W1 via wave-uniform s_loads.
// ---------------------------------------------------------------------------
__global__ __launch_bounds__(64) void k_embproj(
    const float* __restrict__ emb, const float* __restrict__ W1,
    const float* __restrict__ b1, const float* __restrict__ b2,
    float* __restrict__ embW)
{
    const int lane = threadIdx.x;
    const int v = blockIdx.x*64 + lane;
    const float4* ev = (const float4*)(emb + (size_t)v*Dn);
    float e[Dn];
    #pragma unroll
    for (int q = 0; q < Dn/4; ++q){
        float4 x = ev[q];
        e[4*q] = x.x; e[4*q+1] = x.y; e[4*q+2] = x.z; e[4*q+3] = x.w;
    }
    __shared__ float s_out[64*EW];
    #pragma unroll 4
    for (int j = 0; j < Hn; ++j){
        float a0 = b1[j] + b2[j], a1 = 0.f, a2 = 0.f, a3 = 0.f;
        const float* w = W1 + j*Dn;              // uniform -> s_loads
        #pragma unroll
        for (int d = 0; d < Dn; d += 4){
            a0 += w[d]*e[d];     a1 += w[d+1]*e[d+1];
            a2 += w[d+2]*e[d+2]; a3 += w[d+3]*e[d+3];
        }
        s_out[lane*EW + j] = (a0+a1) + (a2+a3);
    }
    #pragma unroll
    for (int j = Hn; j < EW; ++j) s_out[lane*EW + j] = 0.f;
    __syncthreads();
    float* dst = embW + (size_t)blockIdx.x*64*EW;
    for (int i = lane; i < 64*EW; i += 64) dst[i] = s_out[i];
}

// ---------------------------------------------------------------------------
// Sequential scan: ONE WAVE per batch row (256 blocks, 1/CU). Lane L computes
// h[L] and h[64+L]. h broadcast WITHOUT LDS: after sigmoid, pack adjacent
// lanes' f16 via DPP quad_perm[1,0,3,2] (+2cy, no LDS pipe), then 40x
// v_readlane -> SGPR pairs. v_dot2_f32_f16 takes the SGPR operand directly
// (1 SGPR/VALU-instr limit respected). This removes the ~250-350cy/step
// LDS write->read turnaround of the previous version.
// __launch_bounds__(64,1): previous build got VGPR_Count=72 -- too few for
// the 80 resident weight regs, compiler was re-loading w2p every step.
// embW gather prefetched 2 steps ahead. h written to h_all f16 (stride 96).
// ---------------------------------------------------------------------------
__global__ __launch_bounds__(64, 1) void k_rnn(
    const int* __restrict__ X, const float* __restrict__ embW,
    const ushort* __restrict__ w2p, ushort* __restrict__ h_all)
{
    const int b = blockIdx.x;
    const int L = threadIdx.x;
    __shared__ int sX[Sn];
    for (int i = L; i < Sn; i += 64) sX[i] = X[b*Sn + i];
    // W2 rows L and 64+L (clamped; rows >=75 are zero) in registers, packed f16
    uint w1u[40], w2u[40];
    {
        const uint4* r1 = (const uint4*)(w2p + (size_t)L*W2S);
        int L2 = (64 + L < 80) ? (64 + L) : 79;
        const uint4* r2 = (const uint4*)(w2p + (size_t)L2*W2S);
        #pragma unroll
        for (int q = 0; q < 10; ++q){
            uint4 a = r1[q]; uint4 c = r2[q];
            w1u[4*q] = a.x; w1u[4*q+1] = a.y; w1u[4*q+2] = a.z; w1u[4*q+3] = a.w;
            w2u[4*q] = c.x; w2u[4*q+1] = c.y; w2u[4*q+2] = c.z; w2u[4*q+3] = c.w;
        }
    }
    __syncthreads();                           // single wave: trivial

    ushort* hout = h_all + (size_t)b*Sn*KP;
    // xp prefetch pipeline (2 deep): xp1 = embW[tok][L], xp2 = embW[tok][64+L]
    float x1c, x2c, x1n, x2n;
    {
        int t0 = sX[0], t1 = sX[1];
        x1c = embW[(size_t)t0*EW + L];
        x2c = (L < 16) ? embW[(size_t)t0*EW + 64 + L] : 0.f;
        x1n = embW[(size_t)t1*EW + L];
        x2n = (L < 16) ? embW[(size_t)t1*EW + 64 + L] : 0.f;
    }
    // h as 40 wave-uniform f16-pairs (SGPR-resident); h_{-1} = 0
    uint hp[40];
    #pragma unroll
    for (int q = 0; q < 40; ++q) hp[q] = 0u;

    #pragma unroll 2
    for (int s = 0; s < Sn; ++s){
        // issue next-next xp gather early (consumed at s+2)
        int tok = sX[(s+2 < Sn) ? s+2 : Sn-1];
        float x1f = embW[(size_t)tok*EW + L];
        float x2f = (L < 16) ? embW[(size_t)tok*EW + 64 + L] : 0.f;
        // dots: 8 independent chains; xp folded into acc init
        float a0=x1c,a1=0.f,a2=0.f,a3=0.f, c0=x2c,c1=0.f,c2=0.f,c3=0.f;
        #pragma unroll
        for (int p = 0; p < 40; p += 4){
            a0 = __builtin_amdgcn_fdot2(as_h2(w1u[p]),   as_h2(hp[p]),   a0, false);
            a1 = __builtin_amdgcn_fdot2(as_h2(w1u[p+1]), as_h2(hp[p+1]), a1, false);
            a2 = __builtin_amdgcn_fdot2(as_h2(w1u[p+2]), as_h2(hp[p+2]), a2, false);
            a3 = __builtin_amdgcn_fdot2(as_h2(w1u[p+3]), as_h2(hp[p+3]), a3, false);
            c0 = __builtin_amdgcn_fdot2(as_h2(w2u[p]),   as_h2(hp[p]),   c0, false);
            c1 = __builtin_amdgcn_fdot2(as_h2(w2u[p+1]), as_h2(hp[p+1]), c1, false);
            c2 = __builtin_amdgcn_fdot2(as_h2(w2u[p+2]), as_h2(hp[p+2]), c2, false);
            c3 = __builtin_amdgcn_fdot2(as_h2(w2u[p+3]), as_h2(hp[p+3]), c3, false);
        }
        float h1 = sigmoidf((a0+a1)+(a2+a3));
        float h2 = sigmoidf((c0+c1)+(c2+c3));
        if (L >= 11) h2 = 0.f;                 // j = 75..79 pad and beyond
        ushort u1 = f2h(h1);
        ushort u2 = f2h(h2);
        hout[(size_t)s*KP + L] = u1;
        if (L < 16) hout[(size_t)s*KP + 64 + L] = u2;
        // pack adjacent lanes' f16 into pairs (valid on even lanes):
        // partner value via DPP quad_perm [1,0,3,2] -- pure VALU, no LDS
        uint v1 = u1, v2 = u2;
        uint pr1 = (uint)__builtin_amdgcn_update_dpp(0, (int)v1, 0xB1, 0xF, 0xF, true);
        uint pr2 = (uint)__builtin_amdgcn_update_dpp(0, (int)v2, 0xB1, 0xF, 0xF, true);
        uint q1 = v1 | (pr1 << 16);
        uint q2 = v2 | (pr2 << 16);
        // broadcast to SGPRs: pairs 0..31 from even lanes (h[0..63]),
        // pairs 32..39 from even lanes 0..14 of the h2 pack (h[64..79])
        #pragma unroll
        for (int q = 0; q < 32; ++q) hp[q] = (uint)__builtin_amdgcn_readlane((int)q1, 2*q);
        #pragma unroll
        for (int q = 0; q < 8; ++q)  hp[32+q] = (uint)__builtin_amdgcn_readlane((int)q2, 2*q);
        x1c = x1n; x2c = x2n; x1n = x1f; x2n = x2f;
    }
}

// ---------------------------------------------------------------------------
// Epilogue GEMM via MFMA 16x16x32 f16. Per block: 4 waves x 16 rows.
// Phase1: Z = H(16x96)@Wo^T + bo -> sigmoid -> O f16 in LDS (stride 104);
// Phase2: OUT = O@Wfc^T + bfc.
// C/D frag: col=lane&15, row=(lane>>4)*4+reg (m89-verified, dtype-indep).
// ---------------------------------------------------------------------------
__global__ __launch_bounds__(256) void k_out(
    const ushort* __restrict__ h_all, const ushort* __restrict__ woh,
    const ushort* __restrict__ wfh, const float* __restrict__ bo,
    const float* __restrict__ bfc, float* __restrict__ out)
{
    const int lane = threadIdx.x & 63;
    const int w    = threadIdx.x >> 6;
    const size_t r0 = (size_t)blockIdx.x*64 + w*16;
    const int m = lane & 15;
    const int g = lane >> 4;
    __shared__ __align__(16) ushort o_lds[4][16*104];
    ushort* ot = o_lds[w];
    // zero O pad cols 80..95 (read by k-step 2); wave-local, no barrier needed
    for (int i = lane; i < 128; i += 64){
        int row = i >> 3, cw = i & 7;
        *(uint*)&ot[row*104 + 80 + cw*2] = 0u;
    }
    // ---- Phase 1: Z = H @ Wo^T ----
    floatx4 acc1[5] = {};
    const ushort* hbase = h_all + r0*KP;
    #pragma unroll
    for (int ks = 0; ks < 3; ++ks){
        half8 a = *(const half8*)(hbase + (size_t)m*KP + ks*32 + g*8);
        #pragma unroll
        for (int t = 0; t < 5; ++t){
            half8 bt = *(const half8*)(woh + (16*t + m)*KP + ks*32 + g*8);
            acc1[t] = __builtin_amdgcn_mfma_f32_16x16x32_f16(a, bt, acc1[t], 0, 0, 0);
        }
    }
    // ---- bo + sigmoid -> O (f16, C layout) ----
    #pragma unroll
    for (int t = 0; t < 5; ++t){
        int n = 16*t + m;
        float bias = (n < Hn) ? bo[n] : 0.f;
        #pragma unroll
        for (int r = 0; r < 4; ++r){
            int row = g*4 + r;
            float o = sigmoidf(acc1[t][r] + bias);
            if (n >= Hn) o = 0.f;              // pad rows -> z=0 -> 0.5; kill
            ot[row*104 + n] = f2h(o);
        }
    }
    // wave-local LDS RAW: in-order DS pipe within a wave; no barrier
    // ---- Phase 2: OUT = O @ Wfc^T ----
    floatx4 acc2[8] = {};
    #pragma unroll
    for (int ks = 0; ks < 3; ++ks){
        half8 a = *(const half8*)(ot + m*104 + ks*32 + g*8);
        #pragma unroll
        for (int t = 0; t < 8; ++t){
            half8 bt = *(const half8*)(wfh + (16*t + m)*KP + ks*32 + g*8);
            acc2[t] = __builtin_amdgcn_mfma_f32_16x16x32_f16(a, bt, acc2[t], 0, 0, 0);
        }
    }
    // ---- bfc + store ----
    float* orow = out + r0*Ln;
    #pragma unroll
    for (int t = 0; t < 8; ++t){
        float bias = bfc[16*t + m];
        #pragma unroll
        for (int r = 0; r < 4; ++r){
            int row = g*4 + r;
            orow[(size_t)row*Ln + 16*t + m] = acc2[t][r] + bias;
        }
    }
}

extern "C" void kernel_launch(void* const* d_in, const int* in_sizes, int n_in,
                              void* d_out, int out_size, void* d_ws, size_t ws_size,
                              hipStream_t stream)
{
    const int*   X   = (const int*)d_in[0];
    const float* emb = (const float*)d_in[1];
    const float* W1  = (const float*)d_in[2];
    const float* b1  = (const float*)d_in[3];
    const float* W2  = (const float*)d_in[4];
    const float* b2  = (const float*)d_in[5];
    const float* Wo  = (const float*)d_in[6];
    const float* bo  = (const float*)d_in[7];
    const float* Wfc = (const float*)d_in[8];
    const float* bfc = (const float*)d_in[9];
    float* out = (float*)d_out;
    float* ws  = (float*)d_ws;

    float*  embW = ws + OFF_EMBW;
    ushort* hall = (ushort*)(ws + OFF_HALL);
    ushort* w2p  = (ushort*)(ws + OFF_W2P);
    ushort* woh  = (ushort*)(ws + OFF_WOH);
    ushort* wfh  = (ushort*)(ws + OFF_WFH);

    k_wprep<<<dim3(512), dim3(256), 0, stream>>>(W2, Wo, Wfc, w2p, woh, wfh, hall);
    k_embproj<<<dim3(Vn/64), dim3(64), 0, stream>>>(emb, W1, b1, b2, embW);
    k_rnn<<<dim3(Bn), dim3(64), 0, stream>>>(X, embW, w2p, hall);
    k_out<<<dim3((Bn*Sn)/64), dim3(256), 0, stream>>>(hall, woh, wfh, bo, bfc, out);
}

// Round 2
// 398.618 us; speedup vs baseline: 1.0086x; 1.0086x over previous
//
#include <hip/hip_runtime.h>
#include <hip/hip_bf16.h>

typedef unsigned int uint;
typedef unsigned short ushort;

constexpr int Bn = 256, Sn = 512, Vn = 32000, Dn = 100, Hn = 75, Ln = 128;
constexpr int EW = 80;    // embW row stride (floats), cols 75..79 zero
constexpr int KP = 96;    // h_all row stride (f16) = MFMA K-pad (3 x 32)
constexpr int W2S = 80;   // w2p row stride (f16)

// workspace layout (float units)
constexpr size_t OFF_EMBW = 0;                          // 32000*80   = 2,560,000 f
constexpr size_t OFF_HALL = OFF_EMBW + (size_t)Vn*EW;   // 131072*96 f16 = 6,291,456 f
constexpr size_t OFF_W2P  = OFF_HALL + (size_t)Bn*Sn*KP/2; // 80*80 f16 = 3200 f
constexpr size_t OFF_WOH  = OFF_W2P + 3200;             // 80*96 f16  = 3840 f
constexpr size_t OFF_WFH  = OFF_WOH + 3840;             // 128*96 f16 = 6144 f

typedef __attribute__((ext_vector_type(2))) _Float16 half2_t;
typedef __attribute__((ext_vector_type(8))) _Float16 half8;
typedef __attribute__((ext_vector_type(4))) float floatx4;

__device__ __forceinline__ ushort f2h(float f){
    union { _Float16 h; ushort u; } v; v.h = (_Float16)f; return v.u;
}
__device__ __forceinline__ half2_t as_h2(uint u){
    union { uint u; half2_t h; } v; v.u = u; return v.h;
}
__device__ __forceinline__ float sigmoidf(float z){ return 1.f/(1.f + __expf(-z)); }

// ---------------------------------------------------------------------------
// Prep: W2 -> [80][80] f16 (pad 0), Wo -> [80][96] f16, Wfc -> [128][96] f16,
// zero h_all pad cols 80..95 (so k_out never reads garbage).
// ---------------------------------------------------------------------------
__global__ __launch_bounds__(256) void k_wprep(
    const float* __restrict__ W2, const float* __restrict__ Wo,
    const float* __restrict__ Wfc, ushort* __restrict__ w2p,
    ushort* __restrict__ woh, ushort* __restrict__ wfh, ushort* __restrict__ h_all)
{
    const int tid = blockIdx.x*256 + threadIdx.x;
    const int stride = gridDim.x*256;
    for (int i = tid; i < 80*W2S; i += stride){
        int r = i / W2S, k = i % W2S;
        w2p[i] = (r < Hn && k < Hn) ? f2h(W2[r*Hn + k]) : (ushort)0;
    }
    for (int i = tid; i < 80*KP; i += stride){
        int r = i / KP, k = i % KP;
        woh[i] = (r < Hn && k < Hn) ? f2h(Wo[r*Hn + k]) : (ushort)0;
    }
    for (int i = tid; i < Ln*KP; i += stride){
        int l = i / KP, k = i % KP;
        wfh[i] = (k < Hn) ? f2h(Wfc[l*Hn + k]) : (ushort)0;
    }
    // h_all[row][80..95] = 0  (8 uints per row)
    uint* hu = (uint*)h_all;
    for (int i = tid; i < Bn*Sn*8; i += stride){
        int row = i >> 3, c = i & 7;
        hu[(size_t)row*48 + 40 + c] = 0u;
    }
}

// ---------------------------------------------------------------------------
// embW[v][j] = sum_d emb[v][d]*W1[j][d] + b1[j] + b2[j], stride EW=80,
// cols 75..79 zero. One wave per 64 vocab rows; W1 via wave-uniform s_loads.
// ---------------------------------------------------------------------------
__global__ __launch_bounds__(64) void k_embproj(
    const float* __restrict__ emb, const float* __restrict__ W1,
    const float* __restrict__ b1, const float* __restrict__ b2,
    float* __restrict__ embW)
{
    const int lane = threadIdx.x;
    const int v = blockIdx.x*64 + lane;
    const float4* ev = (const float4*)(emb + (size_t)v*Dn);
    float e[Dn];
    #pragma unroll
    for (int q = 0; q < Dn/4; ++q){
        float4 x = ev[q];
        e[4*q] = x.x; e[4*q+1] = x.y; e[4*q+2] = x.z; e[4*q+3] = x.w;
    }
    __shared__ float s_out[64*EW];
    #pragma unroll 4
    for (int j = 0; j < Hn; ++j){
        float a0 = b1[j] + b2[j], a1 = 0.f, a2 = 0.f, a3 = 0.f;
        const float* w = W1 + j*Dn;              // uniform -> s_loads
        #pragma unroll
        for (int d = 0; d < Dn; d += 4){
            a0 += w[d]*e[d];     a1 += w[d+1]*e[d+1];
            a2 += w[d+2]*e[d+2]; a3 += w[d+3]*e[d+3];
        }
        s_out[lane*EW + j] = (a0+a1) + (a2+a3);
    }
    #pragma unroll
    for (int j = Hn; j < EW; ++j) s_out[lane*EW + j] = 0.f;
    __syncthreads();
    float* dst = embW + (size_t)blockIdx.x*64*EW;
    for (int i = lane; i < 64*EW; i += 64) dst[i] = s_out[i];
}

// ---------------------------------------------------------------------------
// Sequential scan: ONE WAVE per batch row (256 blocks, 1/CU). Lane L computes
// h[L] and h[64+L].
// r1 post-mortem: VGPR_Count=52 proved the compiler NEVER kept the 80 weight
// uints resident -- it re-loaded w2p rows from L2 every step (~800cy/step
// stall; L1 thrashed by the embW gather stream). Fix: pass every weight
// element through opaque asm ("+v") after the preload. The values become
// non-rematerializable -> allocator must carry them in VGPRs (512-reg budget
// at 1 wave/SIMD).
// h broadcast stays register-only: sigmoid -> f2h -> DPP quad_perm pack ->
// 40x v_readlane -> SGPR pairs consumed directly by v_dot2_f32_f16.
// embW gather prefetch deepened to 3 steps (step time drops ~3x, 2-deep no
// longer covers L3 latency).
// ---------------------------------------------------------------------------
__global__ __launch_bounds__(64, 1) void k_rnn(
    const int* __restrict__ X, const float* __restrict__ embW,
    const ushort* __restrict__ w2p, ushort* __restrict__ h_all)
{
    const int b = blockIdx.x;
    const int L = threadIdx.x;
    __shared__ int sX[Sn];
    for (int i = L; i < Sn; i += 64) sX[i] = X[b*Sn + i];
    // W2 rows L and 64+L (clamped; rows >=75 are zero) in registers, packed f16
    uint w1u[40], w2u[40];
    {
        const uint4* r1 = (const uint4*)(w2p + (size_t)L*W2S);
        int L2 = (64 + L < 80) ? (64 + L) : 79;
        const uint4* r2 = (const uint4*)(w2p + (size_t)L2*W2S);
        #pragma unroll
        for (int q = 0; q < 10; ++q){
            uint4 a = r1[q]; uint4 c = r2[q];
            w1u[4*q] = a.x; w1u[4*q+1] = a.y; w1u[4*q+2] = a.z; w1u[4*q+3] = a.w;
            w2u[4*q] = c.x; w2u[4*q+1] = c.y; w2u[4*q+2] = c.z; w2u[4*q+3] = c.w;
        }
    }
    // PIN the weights: opaque asm makes them non-rematerializable, forcing
    // true VGPR residency across the scan loop (success check: VGPR_Count>130)
    #pragma unroll
    for (int q = 0; q < 40; ++q){
        asm volatile("" : "+v"(w1u[q]));
        asm volatile("" : "+v"(w2u[q]));
    }
    __syncthreads();                           // single wave: trivial

    ushort* hout = h_all + (size_t)b*Sn*KP;
    // xp prefetch pipeline (3 deep): xp1 = embW[tok][L], xp2 = embW[tok][64+L]
    float x1c, x2c, x1n, x2n, x1m, x2m;
    {
        int t0 = sX[0], t1 = sX[1], t2 = sX[2];
        x1c = embW[(size_t)t0*EW + L];
        x2c = (L < 16) ? embW[(size_t)t0*EW + 64 + L] : 0.f;
        x1n = embW[(size_t)t1*EW + L];
        x2n = (L < 16) ? embW[(size_t)t1*EW + 64 + L] : 0.f;
        x1m = embW[(size_t)t2*EW + L];
        x2m = (L < 16) ? embW[(size_t)t2*EW + 64 + L] : 0.f;
    }
    // h as 40 wave-uniform f16-pairs (SGPR-resident); h_{-1} = 0
    uint hp[40];
    #pragma unroll
    for (int q = 0; q < 40; ++q) hp[q] = 0u;

    #pragma unroll 2
    for (int s = 0; s < Sn; ++s){
        // issue xp gather 3 ahead (consumed at s+3)
        int tok = sX[(s+3 < Sn) ? s+3 : Sn-1];
        float x1f = embW[(size_t)tok*EW + L];
        float x2f = (L < 16) ? embW[(size_t)tok*EW + 64 + L] : 0.f;
        // dots: 8 independent chains; xp folded into acc init
        float a0=x1c,a1=0.f,a2=0.f,a3=0.f, c0=x2c,c1=0.f,c2=0.f,c3=0.f;
        #pragma unroll
        for (int p = 0; p < 40; p += 4){
            a0 = __builtin_amdgcn_fdot2(as_h2(w1u[p]),   as_h2(hp[p]),   a0, false);
            a1 = __builtin_amdgcn_fdot2(as_h2(w1u[p+1]), as_h2(hp[p+1]), a1, false);
            a2 = __builtin_amdgcn_fdot2(as_h2(w1u[p+2]), as_h2(hp[p+2]), a2, false);
            a3 = __builtin_amdgcn_fdot2(as_h2(w1u[p+3]), as_h2(hp[p+3]), a3, false);
            c0 = __builtin_amdgcn_fdot2(as_h2(w2u[p]),   as_h2(hp[p]),   c0, false);
            c1 = __builtin_amdgcn_fdot2(as_h2(w2u[p+1]), as_h2(hp[p+1]), c1, false);
            c2 = __builtin_amdgcn_fdot2(as_h2(w2u[p+2]), as_h2(hp[p+2]), c2, false);
            c3 = __builtin_amdgcn_fdot2(as_h2(w2u[p+3]), as_h2(hp[p+3]), c3, false);
        }
        float h1 = sigmoidf((a0+a1)+(a2+a3));
        float h2 = sigmoidf((c0+c1)+(c2+c3));
        if (L >= 11) h2 = 0.f;                 // j = 75..79 pad and beyond
        ushort u1 = f2h(h1);
        ushort u2 = f2h(h2);
        hout[(size_t)s*KP + L] = u1;
        if (L < 16) hout[(size_t)s*KP + 64 + L] = u2;
        // pack adjacent lanes' f16 into pairs (valid on even lanes):
        // partner value via DPP quad_perm [1,0,3,2] -- pure VALU, no LDS
        uint v1 = u1, v2 = u2;
        uint pr1 = (uint)__builtin_amdgcn_update_dpp(0, (int)v1, 0xB1, 0xF, 0xF, true);
        uint pr2 = (uint)__builtin_amdgcn_update_dpp(0, (int)v2, 0xB1, 0xF, 0xF, true);
        uint q1 = v1 | (pr1 << 16);
        uint q2 = v2 | (pr2 << 16);
        // broadcast to SGPRs: pairs 0..31 from even lanes (h[0..63]),
        // pairs 32..39 from even lanes 0..14 of the h2 pack (h[64..79])
        #pragma unroll
        for (int q = 0; q < 32; ++q) hp[q] = (uint)__builtin_amdgcn_readlane((int)q1, 2*q);
        #pragma unroll
        for (int q = 0; q < 8; ++q)  hp[32+q] = (uint)__builtin_amdgcn_readlane((int)q2, 2*q);
        x1c = x1n; x2c = x2n; x1n = x1m; x2n = x2m; x1m = x1f; x2m = x2f;
    }
}

// ---------------------------------------------------------------------------
// Epilogue GEMM via MFMA 16x16x32 f16. Per block: 4 waves x 16 rows.
// Phase1: Z = H(16x96)@Wo^T + bo -> sigmoid -> O f16 in LDS (stride 104);
// Phase2: OUT = O@Wfc^T + bfc.
// C/D frag: col=lane&15, row=(lane>>4)*4+reg (m89-verified, dtype-indep).
// ---------------------------------------------------------------------------
__global__ __launch_bounds__(256) void k_out(
    const ushort* __restrict__ h_all, const ushort* __restrict__ woh,
    const ushort* __restrict__ wfh, const float* __restrict__ bo,
    const float* __restrict__ bfc, float* __restrict__ out)
{
    const int lane = threadIdx.x & 63;
    const int w    = threadIdx.x >> 6;
    const size_t r0 = (size_t)blockIdx.x*64 + w*16;
    const int m = lane & 15;
    const int g = lane >> 4;
    __shared__ __align__(16) ushort o_lds[4][16*104];
    ushort* ot = o_lds[w];
    // zero O pad cols 80..95 (read by k-step 2); wave-local, no barrier needed
    for (int i = lane; i < 128; i += 64){
        int row = i >> 3, cw = i & 7;
        *(uint*)&ot[row*104 + 80 + cw*2] = 0u;
    }
    // ---- Phase 1: Z = H @ Wo^T ----
    floatx4 acc1[5] = {};
    const ushort* hbase = h_all + r0*KP;
    #pragma unroll
    for (int ks = 0; ks < 3; ++ks){
        half8 a = *(const half8*)(hbase + (size_t)m*KP + ks*32 + g*8);
        #pragma unroll
        for (int t = 0; t < 5; ++t){
            half8 bt = *(const half8*)(woh + (16*t + m)*KP + ks*32 + g*8);
            acc1[t] = __builtin_amdgcn_mfma_f32_16x16x32_f16(a, bt, acc1[t], 0, 0, 0);
        }
    }
    // ---- bo + sigmoid -> O (f16, C layout) ----
    #pragma unroll
    for (int t = 0; t < 5; ++t){
        int n = 16*t + m;
        float bias = (n < Hn) ? bo[n] : 0.f;
        #pragma unroll
        for (int r = 0; r < 4; ++r){
            int row = g*4 + r;
            float o = sigmoidf(acc1[t][r] + bias);
            if (n >= Hn) o = 0.f;              // pad rows -> z=0 -> 0.5; kill
            ot[row*104 + n] = f2h(o);
        }
    }
    // wave-local LDS RAW: in-order DS pipe within a wave; no barrier
    // ---- Phase 2: OUT = O @ Wfc^T ----
    floatx4 acc2[8] = {};
    #pragma unroll
    for (int ks = 0; ks < 3; ++ks){
        half8 a = *(const half8*)(ot + m*104 + ks*32 + g*8);
        #pragma unroll
        for (int t = 0; t < 8; ++t){
            half8 bt = *(const half8*)(wfh + (16*t + m)*KP + ks*32 + g*8);
            acc2[t] = __builtin_amdgcn_mfma_f32_16x16x32_f16(a, bt, acc2[t], 0, 0, 0);
        }
    }
    // ---- bfc + store ----
    float* orow = out + r0*Ln;
    #pragma unroll
    for (int t = 0; t < 8; ++t){
        float bias = bfc[16*t + m];
        #pragma unroll
        for (int r = 0; r < 4; ++r){
            int row = g*4 + r;
            orow[(size_t)row*Ln + 16*t + m] = acc2[t][r] + bias;
        }
    }
}

extern "C" void kernel_launch(void* const* d_in, const int* in_sizes, int n_in,
                              void* d_out, int out_size, void* d_ws, size_t ws_size,
                              hipStream_t stream)
{
    const int*   X   = (const int*)d_in[0];
    const float* emb = (const float*)d_in[1];
    const float* W1  = (const float*)d_in[2];
    const float* b1  = (const float*)d_in[3];
    const float* W2  = (const float*)d_in[4];
    const float* b2  = (const float*)d_in[5];
    const float* Wo  = (const float*)d_in[6];
    const float* bo  = (const float*)d_in[7];
    const float* Wfc = (const float*)d_in[8];
    const float* bfc = (const float*)d_in[9];
    float* out = (float*)d_out;
    float* ws  = (float*)d_ws;

    float*  embW = ws + OFF_EMBW;
    ushort* hall = (ushort*)(ws + OFF_HALL);
    ushort* w2p  = (ushort*)(ws + OFF_W2P);
    ushort* woh  = (ushort*)(ws + OFF_WOH);
    ushort* wfh  = (ushort*)(ws + OFF_WFH);

    k_wprep<<<dim3(512), dim3(256), 0, stream>>>(W2, Wo, Wfc, w2p, woh, wfh, hall);
    k_embproj<<<dim3(Vn/64), dim3(64), 0, stream>>>(emb, W1, b1, b2, embW);
    k_rnn<<<dim3(Bn), dim3(64), 0, stream>>>(X, embW, w2p, hall);
    k_out<<<dim3((Bn*Sn)/64), dim3(256), 0, stream>>>(hall, woh, wfh, bo, bfc, out);
}